// Round 10
// baseline (260.366 us; speedup 1.0000x reference)
//
#include <hip/hip_runtime.h>
#include <hip/hip_bf16.h>
#include <math.h>

// Problem constants
#define LL 4096
#define DD 1024
#define NN 16
#define KK 4
#define BB 2
#define MM (BB * LL)   // 8192
#define NC 128         // scan chunks
#define LC 32          // chunk length (NC*LC == LL)

typedef unsigned short ushort_t;
typedef short s16x8 __attribute__((ext_vector_type(8)));
typedef float f32x4 __attribute__((ext_vector_type(4)));
typedef unsigned int u32;

__device__ __forceinline__ ushort_t f2bf(float f) {
  __hip_bfloat16 h = __float2bfloat16(f);
  return *reinterpret_cast<ushort_t*>(&h);
}
__device__ __forceinline__ float bf2f(ushort_t u) {
  union { u32 i; float f; } c;
  c.i = ((u32)u) << 16;
  return c.f;
}
__device__ __forceinline__ float silu(float v) {
  return v / (1.f + __expf(-v));
}

// ---------------------------------------------------------------------------
// bf16 MFMA GEMM, B-transposed (R8 structure, at its plateau — unchanged):
// 128x128 tile, BK=64, XOR chunk swizzle (conflicts==0), 2D x-fastest grid.
// ---------------------------------------------------------------------------
template <bool BF16OUT>
__global__ __launch_bounds__(256) void gemm_bt_mfma(
    const ushort_t* __restrict__ A,   // [M,K] bf16
    const ushort_t* __restrict__ BT,  // [N,K] bf16
    const float* __restrict__ bias,
    void* __restrict__ Cv, int N) {
  constexpr int K = 1024;
  __shared__ ushort_t As[128 * 64];  // 16 KB
  __shared__ ushort_t Bs[128 * 64];  // 16 KB

  const int tid = threadIdx.x;
  const int lane = tid & 63;
  const int w = tid >> 6;
  const int wm = w & 1, wn = w >> 1;
  const int row0 = blockIdx.y * 128;
  const int col0 = blockIdx.x * 128;

  const int lrow8 = lane >> 3;
  const int lkc = (lane & 7) ^ lrow8;

  f32x4 acc[4][4];
#pragma unroll
  for (int i = 0; i < 4; ++i)
#pragma unroll
    for (int j = 0; j < 4; ++j) acc[i][j] = (f32x4){0.f, 0.f, 0.f, 0.f};

  const int frow = lane & 15;
  const int quad = lane >> 4;
  const int r7 = frow & 7;

  for (int k0 = 0; k0 < K; k0 += 64) {
#pragma unroll
    for (int it = 0; it < 4; ++it) {
      int r = it * 32 + w * 8;
      __builtin_amdgcn_global_load_lds(
          (const __attribute__((address_space(1))) u32*)(A + (size_t)(row0 + r + lrow8) * K + k0 + lkc * 8),
          (__attribute__((address_space(3))) u32*)(As + r * 64), 16, 0, 0);
      __builtin_amdgcn_global_load_lds(
          (const __attribute__((address_space(1))) u32*)(BT + (size_t)(col0 + r + lrow8) * K + k0 + lkc * 8),
          (__attribute__((address_space(3))) u32*)(Bs + r * 64), 16, 0, 0);
    }
    __syncthreads();

#pragma unroll
    for (int half = 0; half < 2; ++half) {
      s16x8 af[4], bf[4];
#pragma unroll
      for (int mi = 0; mi < 4; ++mi)
        af[mi] = *(const s16x8*)&As[(wm * 64 + mi * 16 + frow) * 64 +
                                    (((half * 4 + quad) ^ r7) * 8)];
#pragma unroll
      for (int ni = 0; ni < 4; ++ni)
        bf[ni] = *(const s16x8*)&Bs[(wn * 64 + ni * 16 + frow) * 64 +
                                    (((half * 4 + quad) ^ r7) * 8)];
#pragma unroll
      for (int mi = 0; mi < 4; ++mi)
#pragma unroll
        for (int ni = 0; ni < 4; ++ni)
          acc[mi][ni] = __builtin_amdgcn_mfma_f32_16x16x32_bf16(
              af[mi], bf[ni], acc[mi][ni], 0, 0, 0);
    }
    __syncthreads();
  }

#pragma unroll
  for (int mi = 0; mi < 4; ++mi) {
#pragma unroll
    for (int ni = 0; ni < 4; ++ni) {
      int col = col0 + wn * 64 + ni * 16 + frow;
      float b = bias[col];
#pragma unroll
      for (int r = 0; r < 4; ++r) {
        int row = row0 + wm * 64 + mi * 16 + quad * 4 + r;
        if constexpr (BF16OUT)
          ((ushort_t*)Cv)[(size_t)row * N + col] = f2bf(acc[mi][ni][r] + b);
        else
          ((float*)Cv)[(size_t)row * N + col] = acc[mi][ni][r] + b;
      }
    }
  }
}

// ---------------------------------------------------------------------------
// R10: fused conv+silu+BC-projection. Replaces conv_silu_k + bc_mfma_k and
// eliminates the XCb intermediate. One block per 32-row tile (= one scan
// chunk). Per K-strip of 64 d: threads compute conv+silu in registers from
// XGb (with causal zero-pad at batch start), pack bf16 into a swizzled LDS
// A-tile; WxT strip DMA'd; 2 MFMA per wave per strip (2x2 wave grid).
// ---------------------------------------------------------------------------
__global__ __launch_bounds__(256) void convbc_k(
    const ushort_t* __restrict__ XGb,   // [M,2048] bf16 (x_ssm = cols 0..1023)
    const float* __restrict__ conv_w,   // [1024,4]
    const float* __restrict__ conv_b,   // [1024]
    const ushort_t* __restrict__ WxT,   // [32,1024] bf16
    const float* __restrict__ b_x,      // [32]
    float* __restrict__ BC) {           // [M,32] f32
  constexpr int K = 1024;
  __shared__ ushort_t As[32 * 64];   // 4 KB
  __shared__ ushort_t Bs[32 * 64];   // 4 KB
  __shared__ float cw[128 * 33];     // conv weights, padded (16.9 KB)
  __shared__ float cb[1024];         // conv bias (4 KB)

  const int tid = threadIdx.x;
  const int lane = tid & 63;
  const int w = tid >> 6;            // wave 0..3
  const int wm = w & 1, wn = w >> 1; // 16x16 output tile per wave
  const int row0 = blockIdx.x * 32;
  const int l0 = row0 & (LL - 1);    // position within batch (32 | 4096)

  // stage conv weights (ld=33 to spread banks) + bias, coalesced
#pragma unroll
  for (int j = 0; j < 4; ++j) {
    int d = tid + j * 256;
    float4 v = ((const float4*)conv_w)[d];
    float* p = &cw[(d >> 3) * 33 + (d & 7) * 4];
    p[0] = v.x; p[1] = v.y; p[2] = v.z; p[3] = v.w;
    cb[d] = conv_b[d];
  }
  __syncthreads();

  const int r = tid >> 3;   // 0..31: row within tile
  const int o = tid & 7;    // 0..7: 8-d oct within strip
  const int l = l0 + r;     // in-batch position of this row
  const int frow = lane & 15;
  const int quad = lane >> 4;
  const int lkc = (lane & 7) ^ (lane >> 3);  // B-DMA source chunk swizzle

  f32x4 acc = (f32x4){0.f, 0.f, 0.f, 0.f};

  for (int kk = 0; kk < K; kk += 64) {
    // --- conv+silu for (row r, d = kk+o*8 .. +7) ---
    const ushort_t* xb = XGb + (size_t)(row0 + r) * 2048 + kk + o * 8;
    s16x8 v[4];
#pragma unroll
    for (int k = 0; k < 4; ++k) {
      if (l + k - 3 >= 0)
        v[k] = *(const s16x8*)(xb + (ptrdiff_t)(k - 3) * 2048);
      else
        v[k] = (s16x8){0, 0, 0, 0, 0, 0, 0, 0};
    }
    const int dg = (kk >> 3) + o;
    const float* wp = &cw[dg * 33];
    float a8[8];
#pragma unroll
    for (int j = 0; j < 8; ++j) a8[j] = cb[kk + o * 8 + j];
#pragma unroll
    for (int k = 0; k < 4; ++k)
#pragma unroll
      for (int j = 0; j < 8; ++j)
        a8[j] += bf2f((ushort_t)v[k][j]) * wp[j * 4 + k];
    ushort_t pk[8];
#pragma unroll
    for (int j = 0; j < 8; ++j) pk[j] = f2bf(silu(a8[j]));
    // swizzled A store: slot = o ^ (r&7)
    *(s16x8*)&As[r * 64 + (o ^ (r & 7)) * 8] = *(const s16x8*)pk;

    // --- B strip DMA: wave w stages rows w*8..w*8+7 of WxT ---
    __builtin_amdgcn_global_load_lds(
        (const __attribute__((address_space(1))) u32*)(WxT + (size_t)(w * 8 + (lane >> 3)) * 1024 + kk + lkc * 8),
        (__attribute__((address_space(3))) u32*)(Bs + (w * 8 + (lane >> 3)) * 64), 16, 0, 0);
    __syncthreads();

#pragma unroll
    for (int s = 0; s < 2; ++s) {
      int slot = ((s * 4 + quad) ^ (frow & 7)) * 8;
      s16x8 af = *(const s16x8*)&As[(wm * 16 + frow) * 64 + slot];
      s16x8 bf = *(const s16x8*)&Bs[(wn * 16 + frow) * 64 + slot];
      acc = __builtin_amdgcn_mfma_f32_16x16x32_bf16(af, bf, acc, 0, 0, 0);
    }
    __syncthreads();
  }

  int col = wn * 16 + frow;
  float b = b_x[col];
#pragma unroll
  for (int rr = 0; rr < 4; ++rr) {
    int row = row0 + wm * 16 + quad * 4 + rr;
    BC[(size_t)row * 32 + col] = acc[rr] + b;
  }
}

// ---------------------------------------------------------------------------
// Prep: z=0 -> cast x to bf16 (+ zero fs); z=1 -> weight transposes and
// decay tables Adis=exp(-exp(A_log)), ALC=exp(-LC*exp(A_log)).
// ---------------------------------------------------------------------------
__global__ __launch_bounds__(256) void prep_k(
    const float* __restrict__ x, ushort_t* __restrict__ Xb,
    float* __restrict__ fs, const float* __restrict__ W_in,
    const float* __restrict__ W_out, const float* __restrict__ W_x,
    ushort_t* __restrict__ WinT, ushort_t* __restrict__ WoutT,
    ushort_t* __restrict__ WxT, const float* __restrict__ A_log,
    float* __restrict__ Adis, float* __restrict__ ALC) {
  constexpr int K = 1024;
  const int tid = threadIdx.x;
  if (blockIdx.z == 0) {
    if (blockIdx.x == 0 && blockIdx.y == 0 && tid < 32) fs[tid] = 0.f;
    int i = (blockIdx.y * 64 + blockIdx.x) * 256 + tid;
    float4 v = ((const float4*)x)[i];
    ushort4 o;
    o.x = f2bf(v.x); o.y = f2bf(v.y); o.z = f2bf(v.z); o.w = f2bf(v.w);
    ((ushort4*)Xb)[i] = o;
    return;
  }
  int by = blockIdx.y;
  if (by >= 96) {
    if (by >= 104 || blockIdx.x != 0) return;
    int base = (by - 96) * 2048 + tid * 8;
#pragma unroll
    for (int j = 0; j < 8; ++j) {
      float e = __expf(A_log[base + j]);
      Adis[base + j] = __expf(-e);
      ALC[base + j] = __expf(-(float)LC * e);
    }
    return;
  }
  const float* W;
  ushort_t* WT;
  int N;
  if (by < 32) {
    W = W_in; WT = WinT; N = 2048;
  } else if (by < 64) {
    if (blockIdx.x >= 32) return;
    W = W_out; WT = WoutT; N = 1024;
    by -= 32;
  } else {
    if (blockIdx.x >= 1) return;
    W = W_x; WT = WxT; N = 32;
    by -= 64;
  }
  __shared__ float t[32][33];
  int nb = blockIdx.x * 32, kb = by * 32;
  int tx = tid & 31, ty = tid >> 5;  // (32,8)
#pragma unroll
  for (int i = 0; i < 32; i += 8)
    t[ty + i][tx] = W[(size_t)(kb + ty + i) * N + nb + tx];
  __syncthreads();
#pragma unroll
  for (int i = 0; i < 32; i += 8)
    WT[(size_t)(nb + ty + i) * K + kb + tx] = f2bf(t[tx][ty + i]);
}

// ---------------------------------------------------------------------------
// Scan phase 1: per-chunk local scan from h=0 with ON-THE-FLY conv+silu
// (4-deep rolling window over XGb rows; same load count as the old XCb read,
// xc stays f32 — closer to reference). 4 waves/block, wave-private LDS,
// zero barriers after staging. S layout [b][c][n][d].
// ---------------------------------------------------------------------------
__global__ __launch_bounds__(256) void scan_local_k(
    const ushort_t* __restrict__ XGb, const float* __restrict__ BC,
    const float* __restrict__ Adis, const float* __restrict__ conv_w,
    const float* __restrict__ conv_b, float* __restrict__ S) {
  const int b = blockIdx.x;
  const int w = threadIdx.x >> 6;
  const int lane = threadIdx.x & 63;
  const int c = blockIdx.y * 4 + w;
  const int d0 = blockIdx.z * 128 + lane * 2;
  const int t0 = c * LC;
  const size_t rowb = (size_t)b * LL;

  __shared__ float bcs_all[4][LC * 32];
  float* bcs = bcs_all[w];
  {
    const float4* src = (const float4*)(BC + (rowb + t0) * 32);
    float4* dst = (float4*)bcs;
#pragma unroll
    for (int i = 0; i < 4; ++i) dst[lane + i * 64] = src[lane + i * 64];
  }
  f32x4 av[8];
#pragma unroll
  for (int i = 0; i < 8; ++i) av[i] = *(const f32x4*)(Adis + d0 * 16 + i * 4);
  float4 w0 = ((const float4*)conv_w)[d0];
  float4 w1 = ((const float4*)conv_w)[d0 + 1];
  float2 cb2 = *(const float2*)(conv_b + d0);

  float h0[NN], h1[NN];
#pragma unroll
  for (int n = 0; n < NN; ++n) { h0[n] = 0.f; h1[n] = 0.f; }

  const ushort_t* xbase = XGb + rowb * 2048 + d0;  // x_ssm half
  u32 win[4];
#pragma unroll
  for (int k = 0; k < 4; ++k) {
    int l = t0 - 3 + k;
    win[k] = (l >= 0) ? *(const u32*)(xbase + (size_t)l * 2048) : 0u;
  }
  for (int t = 0; t < LC; ++t) {
    u32 win_n = (t + 1 < LC) ? *(const u32*)(xbase + (size_t)(t0 + t + 1) * 2048) : 0u;
    float v0 = cb2.x, v1 = cb2.y;
#pragma unroll
    for (int k = 0; k < 4; ++k) {
      float wk0 = (k == 0) ? w0.x : (k == 1) ? w0.y : (k == 2) ? w0.z : w0.w;
      float wk1 = (k == 0) ? w1.x : (k == 1) ? w1.y : (k == 2) ? w1.z : w1.w;
      v0 += bf2f((ushort_t)(win[k] & 0xffff)) * wk0;
      v1 += bf2f((ushort_t)(win[k] >> 16)) * wk1;
    }
    float x0 = silu(v0), x1 = silu(v1);
    const float* bp = bcs + t * 32;
#pragma unroll
    for (int n = 0; n < NN; ++n) {
      float bv = bp[n];
      h0[n] = av[n >> 2][n & 3] * h0[n] + x0 * bv;
      h1[n] = av[4 + (n >> 2)][n & 3] * h1[n] + x1 * bv;
    }
    win[0] = win[1]; win[1] = win[2]; win[2] = win[3]; win[3] = win_n;
  }
  float* sp = S + ((size_t)(b * NC + c) * NN) * DD + d0;
#pragma unroll
  for (int n = 0; n < NN; ++n) {
    float2 v = {h0[n], h1[n]};
    *(float2*)(sp + (size_t)n * DD) = v;
  }
}

// ---------------------------------------------------------------------------
// Scan phase 2: sequential carry over chunks (S -> H0 in place) + fs mean.
// R10: explicit next-chunk prefetch so the load leaves before the FMA chain.
// ---------------------------------------------------------------------------
__global__ __launch_bounds__(256) void scan_carry_k(
    float* __restrict__ S, const float* __restrict__ ALC,
    float* __restrict__ fs) {
  const int idx = blockIdx.x * 256 + threadIdx.x;
  const int d = idx & (DD - 1);
  const int n = (idx >> 10) & (NN - 1);
  const int b = idx >> 14;

  const float aLC = ALC[d * NN + n];
  const size_t base = ((size_t)b * NC * NN + n) * DD + d;
  const size_t step = (size_t)NN * DD;
  float h = 0.f;
  float s = S[base];
  for (int c = 0; c < NC; ++c) {
    float s_n = (c + 1 < NC) ? S[base + (size_t)(c + 1) * step] : 0.f;
    S[base + (size_t)c * step] = h;
    h = aLC * h + s;
    s = s_n;
  }
  __shared__ float red[256];
  red[threadIdx.x] = h;
  __syncthreads();
#pragma unroll
  for (int s2 = 128; s2 > 0; s2 >>= 1) {
    if (threadIdx.x < s2) red[threadIdx.x] += red[threadIdx.x + s2];
    __syncthreads();
  }
  if (threadIdx.x == 0) atomicAdd(&fs[b * NN + n], red[0] * (1.f / (float)DD));
}

// ---------------------------------------------------------------------------
// Scan phase 3: replay from H0 with on-the-fly conv, y*silu(gate) -> Y1b.
// ---------------------------------------------------------------------------
__global__ __launch_bounds__(256) void scan_final_k(
    const ushort_t* __restrict__ XGb, const float* __restrict__ BC,
    const float* __restrict__ Adis, const float* __restrict__ conv_w,
    const float* __restrict__ conv_b, const float* __restrict__ D_param,
    const float* __restrict__ H0, ushort_t* __restrict__ Y1b) {
  const int b = blockIdx.x;
  const int w = threadIdx.x >> 6;
  const int lane = threadIdx.x & 63;
  const int c = blockIdx.y * 4 + w;
  const int d0 = blockIdx.z * 128 + lane * 2;
  const int t0 = c * LC;
  const size_t rowb = (size_t)b * LL;

  __shared__ float bcs_all[4][LC * 32];
  float* bcs = bcs_all[w];
  {
    const float4* src = (const float4*)(BC + (rowb + t0) * 32);
    float4* dst = (float4*)bcs;
#pragma unroll
    for (int i = 0; i < 4; ++i) dst[lane + i * 64] = src[lane + i * 64];
  }
  f32x4 av[8];
#pragma unroll
  for (int i = 0; i < 8; ++i) av[i] = *(const f32x4*)(Adis + d0 * 16 + i * 4);
  float4 w0 = ((const float4*)conv_w)[d0];
  float4 w1 = ((const float4*)conv_w)[d0 + 1];
  float2 cb2 = *(const float2*)(conv_b + d0);

  float h0[NN], h1[NN];
  const float* hp = H0 + ((size_t)(b * NC + c) * NN) * DD + d0;
#pragma unroll
  for (int n = 0; n < NN; ++n) {
    float2 v = *(const float2*)(hp + (size_t)n * DD);
    h0[n] = v.x;
    h1[n] = v.y;
  }
  float2 Dp = *(const float2*)(D_param + d0);

  const ushort_t* xbase = XGb + rowb * 2048 + d0;         // x_ssm half
  const ushort_t* gbase = XGb + rowb * 2048 + DD + d0;    // gate half
  ushort_t* yp = Y1b + (rowb + t0) * DD + d0;
  u32 win[4];
#pragma unroll
  for (int k = 0; k < 4; ++k) {
    int l = t0 - 3 + k;
    win[k] = (l >= 0) ? *(const u32*)(xbase + (size_t)l * 2048) : 0u;
  }
  u32 gw = *(const u32*)(gbase + (size_t)t0 * 2048);
  for (int t = 0; t < LC; ++t) {
    u32 win_n = 0u, gw_n = 0u;
    if (t + 1 < LC) {
      win_n = *(const u32*)(xbase + (size_t)(t0 + t + 1) * 2048);
      gw_n = *(const u32*)(gbase + (size_t)(t0 + t + 1) * 2048);
    }
    float v0 = cb2.x, v1 = cb2.y;
#pragma unroll
    for (int k = 0; k < 4; ++k) {
      float wk0 = (k == 0) ? w0.x : (k == 1) ? w0.y : (k == 2) ? w0.z : w0.w;
      float wk1 = (k == 0) ? w1.x : (k == 1) ? w1.y : (k == 2) ? w1.z : w1.w;
      v0 += bf2f((ushort_t)(win[k] & 0xffff)) * wk0;
      v1 += bf2f((ushort_t)(win[k] >> 16)) * wk1;
    }
    float x0 = silu(v0), x1 = silu(v1);
    float g0 = bf2f((ushort_t)(gw & 0xffff));
    float g1 = bf2f((ushort_t)(gw >> 16));
    float y0 = Dp.x * x0, y1 = Dp.y * x1;
    const float* bp = bcs + t * 32;
#pragma unroll
    for (int n = 0; n < NN; ++n) {
      float bv = bp[n], cv = bp[16 + n];
      h0[n] = av[n >> 2][n & 3] * h0[n] + x0 * bv;
      h1[n] = av[4 + (n >> 2)][n & 3] * h1[n] + x1 * bv;
      y0 += cv * h0[n];
      y1 += cv * h1[n];
    }
    u32 outw = (u32)f2bf(y0 * silu(g0)) | ((u32)f2bf(y1 * silu(g1)) << 16);
    *(u32*)(yp + (size_t)t * DD) = outw;
    win[0] = win[1]; win[1] = win[2]; win[2] = win[3]; win[3] = win_n;
    gw = gw_n;
  }
}

// ---------------------------------------------------------------------------
extern "C" void kernel_launch(void* const* d_in, const int* in_sizes, int n_in,
                              void* d_out, int out_size, void* d_ws,
                              size_t ws_size, hipStream_t stream) {
  const float* x = (const float*)d_in[0];
  const float* W_in = (const float*)d_in[1];
  const float* b_in = (const float*)d_in[2];
  const float* conv_w = (const float*)d_in[3];
  const float* conv_b = (const float*)d_in[4];
  const float* W_x = (const float*)d_in[5];
  const float* b_x = (const float*)d_in[6];
  const float* A_log = (const float*)d_in[7];
  const float* D_param = (const float*)d_in[8];
  const float* W_out = (const float*)d_in[9];
  const float* b_out = (const float*)d_in[10];
  float* out = (float*)d_out;
  float* fs = out + (size_t)MM * DD;

  // ws layout: f32 regions then bf16 regions (all 16B-aligned)
  float* BC = (float*)d_ws;                    // [8192*32] f32
  float* S = BC + (size_t)MM * 32;             // [2*128*16*1024] f32
  float* Adis = S + (size_t)BB * NC * NN * DD; // [1024*16] f32
  float* ALC = Adis + (size_t)DD * NN;         // [1024*16] f32
  ushort_t* Xb = (ushort_t*)(ALC + (size_t)DD * NN);  // [8192*1024] bf16
  ushort_t* XGb = Xb + (size_t)MM * DD;        // [8192*2048] bf16
  ushort_t* Y1b = XGb + (size_t)MM * 2048;     // [8192*1024] bf16
  ushort_t* WinT = Y1b + (size_t)MM * DD;      // [2048*1024] bf16
  ushort_t* WoutT = WinT + (size_t)2048 * DD;  // [1024*1024] bf16
  ushort_t* WxT = WoutT + (size_t)DD * DD;     // [32*1024] bf16

  dim3 blk(256);
  // 1. prep: cast x, fs zero, weight transposes, decay tables
  prep_k<<<dim3(64, 128, 2), blk, 0, stream>>>(x, Xb, fs, W_in, W_out, W_x,
                                               WinT, WoutT, WxT, A_log, Adis,
                                               ALC);
  // 2. in-proj (bf16 MFMA, bf16 out): XGb = x @ W_in + b_in
  gemm_bt_mfma<true><<<dim3(2048 / 128, MM / 128), blk, 0, stream>>>(
      Xb, WinT, b_in, XGb, 2048);
  // 3. fused conv+silu+BC-proj: BC = silu(conv(x_ssm)) @ W_x + b_x
  convbc_k<<<dim3(MM / 32), blk, 0, stream>>>(XGb, conv_w, conv_b, WxT, b_x,
                                              BC);
  // 4. scan phase 1 (on-the-fly conv, barrier-free waves)
  scan_local_k<<<dim3(BB, NC / 4, DD / 128), blk, 0, stream>>>(
      XGb, BC, Adis, conv_w, conv_b, S);
  // 5. carry + final-state mean
  scan_carry_k<<<dim3((BB * DD * NN) / 256), blk, 0, stream>>>(S, ALC, fs);
  // 6. scan phase 3 (on-the-fly conv) -> Y1 bf16
  scan_final_k<<<dim3(BB, NC / 4, DD / 128), blk, 0, stream>>>(
      XGb, BC, Adis, conv_w, conv_b, D_param, S, Y1b);
  // 7. out-proj (bf16 MFMA, f32 out): out = Y1 @ W_out + b_out
  gemm_bt_mfma<false><<<dim3(1024 / 128, MM / 128), blk, 0, stream>>>(
      Y1b, WoutT, b_out, out, 1024);
}